// Round 10
// baseline (83.454 us; speedup 1.0000x reference)
//
#include <hip/hip_runtime.h>
#include <hip/hip_bf16.h>

typedef __attribute__((ext_vector_type(4))) float f32x4;
typedef __attribute__((ext_vector_type(4))) int i32x4;
typedef __attribute__((ext_vector_type(8))) short bf16x8;
typedef __attribute__((ext_vector_type(16))) float f32x16;
typedef long i64t;

#define MSZ 8192
#define D_DIM 256
#define PM 64          // rows per block panel
#define PN 64          // cols per tile
#define NT2 16         // tiles per block (col span 1024)

#define GLOAD_LDS(g, s) __builtin_amdgcn_global_load_lds( \
    (const __attribute__((address_space(1))) unsigned int*)(g), \
    (__attribute__((address_space(3))) unsigned int*)(s), 16, 0, 0)

__device__ __forceinline__ unsigned short f2bf(float f) {
  __hip_bfloat16 h = __float2bfloat16(f);
  unsigned short u; __builtin_memcpy(&u, &h, 2); return u;
}

// ---------------- pass 1: Y only: fp32 -> fp8(e4m3) + exact fp32 row norms ----------------
__global__ __launch_bounds__(256)
void prep_y(const float* __restrict__ Y, unsigned char* __restrict__ Yq,
            float* __restrict__ y2) {
  int gw = (blockIdx.x * 256 + threadIdx.x) >> 6;   // one wave per row; 8192 waves
  int l = threadIdx.x & 63;
  const float* src = Y + (size_t)gw * D_DIM + l * 4;
  f32x4 v = *(const f32x4*)src;
  float ss = v[0]*v[0] + v[1]*v[1] + v[2]*v[2] + v[3]*v[3];
  int p = __builtin_amdgcn_cvt_pk_fp8_f32(v[0], v[1], 0, false);
  p = __builtin_amdgcn_cvt_pk_fp8_f32(v[2], v[3], p, true);
  *(unsigned int*)(Yq + (size_t)gw * D_DIM + l * 4) = (unsigned int)p;
  #pragma unroll
  for (int m = 1; m < 64; m <<= 1) ss += __shfl_xor(ss, m);
  if (l == 0) y2[gw] = ss;
}

// -- pass 2: r9 structure + in-block X quantization + nt output stores --
__global__ __launch_bounds__(256, 4)
void rbf_main(const float* __restrict__ X, const unsigned char* __restrict__ Yq,
              const float* __restrict__ Y2, float* __restrict__ Out) {
  __shared__ __align__(16) unsigned char Al[PM * D_DIM];   // 16 KB, built once (in-block cvt)
  __shared__ __align__(16) unsigned char Bl[PN * D_DIM];   // 16 KB, restaged per tile
  __shared__ float sx2[PM];                                 // 256 B (computed in-block)
  __shared__ float sy2l[NT2 * PN];                          // 4 KB: all 16 tiles' col norms

  int bid = blockIdx.x;                  // 1024 blocks; 1024 % 8 == 0 -> bijective swizzle
  int swz = (bid & 7) * 128 + (bid >> 3);
  int bm = swz >> 3;                     // 128 row-panels of 64
  int cg = swz & 7;                      // 8 column groups of 1024
  int rowBase = bm * PM;
  int colBase = cg * (PN * NT2);

  int tid = threadIdx.x;
  int l = tid & 63;
  int w = tid >> 6;                      // 4 waves, 2x2 grid of 32x32 sub-tiles
  int wr = w >> 1, wc = w & 1;
  int sk = l & 15;                       // LDS granule swizzle key

  *(f32x4*)&sy2l[tid * 4] = *(const f32x4*)&Y2[colBase + tid * 4];   // 1024 floats

  // --- B tile 0 staging first (DMA flies while we convert A in VALU) ---
  #pragma unroll
  for (int q = 0; q < 4; ++q) {
    int c = tid + 256 * q;
    int row = c >> 4, g = c & 15;
    GLOAD_LDS(Yq + (size_t)(colBase + row) * D_DIM + ((g ^ (row & 15)) << 4), Bl + c * 16);
  }

  // --- in-block A panel: 4 threads/row, each converts 64 fp32 -> 64 fp8 + norm part ---
  {
    int arow = tid >> 2;                 // 0..63
    int part = tid & 3;                  // 64-float chunk
    const float* xsrc = X + (size_t)(rowBase + arow) * D_DIM + part * 64;
    float ss = 0.0f;
    #pragma unroll
    for (int g4 = 0; g4 < 4; ++g4) {     // 4 granules of 16 fp8 bytes each
      i32x4 pk;
      #pragma unroll
      for (int d = 0; d < 4; ++d) {
        f32x4 v = *(const f32x4*)(xsrc + g4 * 16 + d * 4);
        ss += v[0]*v[0] + v[1]*v[1] + v[2]*v[2] + v[3]*v[3];
        int p = __builtin_amdgcn_cvt_pk_fp8_f32(v[0], v[1], 0, false);
        p = __builtin_amdgcn_cvt_pk_fp8_f32(v[2], v[3], p, true);
        pk[d] = p;
      }
      int gg = part * 4 + g4;            // global granule 0..15 in row
      *(i32x4*)(Al + arow * D_DIM + ((gg ^ (arow & 15)) << 4)) = pk;
    }
    ss += __shfl_xor(ss, 1);
    ss += __shfl_xor(ss, 2);
    if (part == 0) sx2[arow] = ss;
  }

  asm volatile("s_waitcnt vmcnt(0)" ::: "memory");
  __syncthreads();                       // tile 0 staged + Al/sx2/sy2l visible

  const unsigned char* Abase = Al + (wr * 32 + (l & 31)) * D_DIM + ((l >> 5) << 3);
  const unsigned char* Bbase = Bl + (wc * 32 + (l & 31)) * D_DIM + ((l >> 5) << 3);
  int rb0 = wr * 32 + 4 * (l >> 5);
  float sxv[16];
  #pragma unroll
  for (int q = 0; q < 16; ++q)           // hoist row norms to registers (static idx)
    sxv[q] = sx2[rb0 + (q & 3) + 8 * (q >> 2)];

  #pragma unroll 1
  for (int tt = 0; tt < NT2; ++tt) {
    // steady state queue per wave/tile = [4 staging][16 stores]; vmcnt(16) drains
    // old stores + all 4 staging ops, leaves 16 newest stores in flight (m135).
    if (tt) {
      asm volatile("s_waitcnt vmcnt(16)" ::: "memory");
      __builtin_amdgcn_s_barrier();      // Bl staged by ALL waves
    }
    __builtin_amdgcn_sched_barrier(0);

    // --- compute: K=256 in 16 x v_mfma_f32_32x32x16_fp8_fp8 (one 32x32 per wave) ---
    f32x16 acc = {};
    #pragma unroll
    for (int kk = 0; kk < 16; ++kk) {
      int ca = (kk ^ sk) << 4;
      i64t a = *(const i64t*)(Abase + ca);
      i64t b = *(const i64t*)(Bbase + ca);
      acc = __builtin_amdgcn_mfma_f32_32x32x16_fp8_fp8(a, b, acc, 0, 0, 0);
    }
    __builtin_amdgcn_s_barrier();        // all waves done reading Bl -> restage safe
    asm volatile("" ::: "memory");

    // --- issue NEXT tile's staging (4 vmem ops) BEFORE this tile's stores ---
    if (tt + 1 < NT2) {
      int colN = colBase + (tt + 1) * PN;
      #pragma unroll
      for (int q = 0; q < 4; ++q) {
        int c = tid + 256 * q;
        int row = c >> 4, g = c & 15;
        GLOAD_LDS(Yq + (size_t)(colN + row) * D_DIM + ((g ^ (row & 15)) << 4), Bl + c * 16);
      }
    }
    asm volatile("" ::: "memory");       // keep stores below the staging issues

    // --- epilogue: exp + 16 nt dword stores (half-wave = one full 128B line) ---
    // C/D layout: col = l&31, row = (q&3) + 8*(q>>2) + 4*(l>>5)   [m74/m101]
    float sy = sy2l[tt * PN + wc * 32 + (l & 31)];
    float* base = Out + (size_t)(rowBase + rb0) * MSZ + colBase + tt * PN + wc * 32 + (l & 31);
    #pragma unroll
    for (int q = 0; q < 16; ++q) {
      int rpat = (q & 3) + 8 * (q >> 2);
      float d = fmaf(-2.0f, acc[q], sxv[q] + sy);
      __builtin_nontemporal_store(__expf(-fmaxf(d, 0.0f)), base + (size_t)rpat * MSZ);
    }
    asm volatile("" ::: "memory");
  }
}

// ---------------- fallback (bf16, self-contained, used only if ws too small) ----------------
__global__ __launch_bounds__(256, 2)
void rbf_mfma_kernel(const float* __restrict__ X, const float* __restrict__ Y,
                     float* __restrict__ Out) {
  __shared__ unsigned short As[128 * 64];
  __shared__ unsigned short Bs[128 * 64];
  __shared__ float sx2[128];
  __shared__ float sy2[128];
  int bid = blockIdx.x;
  int cpx = gridDim.x >> 3;
  int swz = (bid & 7) * cpx + (bid >> 3);
  int bm = swz >> 6, bn = swz & 63;
  int rowBase = bm * 128, colBase = bn * 128;
  int tid = threadIdx.x;
  int l = tid & 63;
  int w = tid >> 6;
  int wr = w >> 1, wc = w & 1;
  f32x4 acc[4][4] = {};
  float assq[4] = {0.f,0.f,0.f,0.f};
  float bssq[4] = {0.f,0.f,0.f,0.f};
  for (int ks = 0; ks < D_DIM / 64; ++ks) {
    if (ks) __syncthreads();
    #pragma unroll
    for (int p = 0; p < 4; ++p) {
      int c = tid + 256 * p;
      int r = c >> 3;
      int kc = c & 7;
      const float* gx = X + (size_t)(rowBase + r) * D_DIM + ks * 64 + kc * 8;
      const float* gy = Y + (size_t)(colBase + r) * D_DIM + ks * 64 + kc * 8;
      f32x4 xa = *(const f32x4*)gx;
      f32x4 xb = *(const f32x4*)(gx + 4);
      f32x4 ya = *(const f32x4*)gy;
      f32x4 yb = *(const f32x4*)(gy + 4);
      #pragma unroll
      for (int j = 0; j < 4; ++j) {
        assq[p] += xa[j]*xa[j] + xb[j]*xb[j];
        bssq[p] += ya[j]*ya[j] + yb[j]*yb[j];
      }
      union { bf16x8 v; unsigned short u[8]; } pa, pb;
      #pragma unroll
      for (int j = 0; j < 4; ++j) {
        pa.u[j] = f2bf(xa[j]);  pa.u[j+4] = f2bf(xb[j]);
        pb.u[j] = f2bf(ya[j]);  pb.u[j+4] = f2bf(yb[j]);
      }
      int boff = (r * 128 + kc * 16) ^ ((r & 7) << 4);
      *(bf16x8*)((char*)As + boff) = pa.v;
      *(bf16x8*)((char*)Bs + boff) = pb.v;
    }
    __syncthreads();
    #pragma unroll
    for (int kk = 0; kk < 2; ++kk) {
      bf16x8 af[4], bfv[4];
      #pragma unroll
      for (int i = 0; i < 4; ++i) {
        int ra = wr*64 + i*16 + (l & 15);
        int offa = (ra * 128 + kk*64 + (l >> 4) * 16) ^ ((ra & 7) << 4);
        af[i] = *(bf16x8*)((char*)As + offa);
        int rb = wc*64 + i*16 + (l & 15);
        int offb = (rb * 128 + kk*64 + (l >> 4) * 16) ^ ((rb & 7) << 4);
        bfv[i] = *(bf16x8*)((char*)Bs + offb);
      }
      #pragma unroll
      for (int i = 0; i < 4; ++i)
        #pragma unroll
        for (int j = 0; j < 4; ++j)
          acc[i][j] = __builtin_amdgcn_mfma_f32_16x16x32_bf16(af[i], bfv[j], acc[i][j], 0, 0, 0);
    }
  }
  #pragma unroll
  for (int p = 0; p < 4; ++p) {
    float a = assq[p], b = bssq[p];
    a += __shfl_xor(a, 1); b += __shfl_xor(b, 1);
    a += __shfl_xor(a, 2); b += __shfl_xor(b, 2);
    a += __shfl_xor(a, 4); b += __shfl_xor(b, 4);
    if ((tid & 7) == 0) {
      int r = (tid >> 3) + 32 * p;
      sx2[r] = a;
      sy2[r] = b;
    }
  }
  __syncthreads();
  #pragma unroll
  for (int i = 0; i < 4; ++i)
    #pragma unroll
    for (int j = 0; j < 4; ++j)
      #pragma unroll
      for (int q = 0; q < 4; ++q) {
        int rn = wr*64 + i*16 + (l >> 4) * 4 + q;
        int cm = wc*64 + j*16 + (l & 15);
        float d2 = sx2[rn] + sy2[cm] - 2.0f * acc[i][j][q];
        Out[(size_t)(rowBase + rn) * MSZ + (colBase + cm)] = __expf(-fmaxf(d2, 0.0f));
      }
}

extern "C" void kernel_launch(void* const* d_in, const int* in_sizes, int n_in,
                              void* d_out, int out_size, void* d_ws, size_t ws_size,
                              hipStream_t stream) {
  const float* X = (const float*)d_in[0];
  const float* Y = (const float*)d_in[1];
  float* Out = (float*)d_out;
  const size_t QB = (size_t)MSZ * D_DIM;               // 2 MiB (fp8 Y)
  const size_t NEED = QB + (size_t)MSZ * 4;            // Yq + y2
  if (ws_size >= NEED) {
    unsigned char* Yq = (unsigned char*)d_ws;
    float* y2 = (float*)(Yq + QB);
    prep_y<<<dim3(2048), dim3(256), 0, stream>>>(Y, Yq, y2);
    rbf_main<<<dim3(1024), dim3(256), 0, stream>>>(X, Yq, y2, Out);
  } else {
    rbf_mfma_kernel<<<dim3(64 * 64), dim3(256), 0, stream>>>(X, Y, Out);
  }
}

// Round 11
// 66.730 us; speedup vs baseline: 1.2506x; 1.2506x over previous
//
#include <hip/hip_runtime.h>
#include <hip/hip_bf16.h>

typedef __attribute__((ext_vector_type(4))) float f32x4;
typedef __attribute__((ext_vector_type(4))) int i32x4;
typedef __attribute__((ext_vector_type(8))) short bf16x8;
typedef __attribute__((ext_vector_type(16))) float f32x16;
typedef long i64t;

#define MSZ 8192
#define D_DIM 256
#define PM 64          // rows per block panel
#define PN 64          // cols per tile
#define NT2 16         // tiles per block (col span 1024)

#define GLOAD_LDS(g, s) __builtin_amdgcn_global_load_lds( \
    (const __attribute__((address_space(1))) unsigned int*)(g), \
    (__attribute__((address_space(3))) unsigned int*)(s), 16, 0, 0)

__device__ __forceinline__ unsigned short f2bf(float f) {
  __hip_bfloat16 h = __float2bfloat16(f);
  unsigned short u; __builtin_memcpy(&u, &h, 2); return u;
}

// ---------------- pass 1: Y only: fp32 -> fp8(e4m3) + exact fp32 row norms ----------------
__global__ __launch_bounds__(256)
void prep_y(const float* __restrict__ Y, unsigned char* __restrict__ Yq,
            float* __restrict__ y2) {
  int gw = (blockIdx.x * 256 + threadIdx.x) >> 6;   // one wave per row; 8192 waves
  int l = threadIdx.x & 63;
  const float* src = Y + (size_t)gw * D_DIM + l * 4;
  f32x4 v = *(const f32x4*)src;
  float ss = v[0]*v[0] + v[1]*v[1] + v[2]*v[2] + v[3]*v[3];
  int p = __builtin_amdgcn_cvt_pk_fp8_f32(v[0], v[1], 0, false);
  p = __builtin_amdgcn_cvt_pk_fp8_f32(v[2], v[3], p, true);
  *(unsigned int*)(Yq + (size_t)gw * D_DIM + l * 4) = (unsigned int)p;
  #pragma unroll
  for (int m = 1; m < 64; m <<= 1) ss += __shfl_xor(ss, m);
  if (l == 0) y2[gw] = ss;
}

// -- pass 2: r9 structure + in-block X quantization; PLAIN dword stores (nt reverted) --
__global__ __launch_bounds__(256, 4)
void rbf_main(const float* __restrict__ X, const unsigned char* __restrict__ Yq,
              const float* __restrict__ Y2, float* __restrict__ Out) {
  __shared__ __align__(16) unsigned char Al[PM * D_DIM];   // 16 KB, built once (in-block cvt)
  __shared__ __align__(16) unsigned char Bl[PN * D_DIM];   // 16 KB, restaged per tile
  __shared__ float sx2[PM];                                 // 256 B (computed in-block)
  __shared__ float sy2l[NT2 * PN];                          // 4 KB: all 16 tiles' col norms

  int bid = blockIdx.x;                  // 1024 blocks; 1024 % 8 == 0 -> bijective swizzle
  int swz = (bid & 7) * 128 + (bid >> 3);
  int bm = swz >> 3;                     // 128 row-panels of 64
  int cg = swz & 7;                      // 8 column groups of 1024
  int rowBase = bm * PM;
  int colBase = cg * (PN * NT2);

  int tid = threadIdx.x;
  int l = tid & 63;
  int w = tid >> 6;                      // 4 waves, 2x2 grid of 32x32 sub-tiles
  int wr = w >> 1, wc = w & 1;
  int sk = l & 15;                       // LDS granule swizzle key

  *(f32x4*)&sy2l[tid * 4] = *(const f32x4*)&Y2[colBase + tid * 4];   // 1024 floats

  // --- B tile 0 staging first (DMA flies while we convert A in VALU) ---
  #pragma unroll
  for (int q = 0; q < 4; ++q) {
    int c = tid + 256 * q;
    int row = c >> 4, g = c & 15;
    GLOAD_LDS(Yq + (size_t)(colBase + row) * D_DIM + ((g ^ (row & 15)) << 4), Bl + c * 16);
  }

  // --- in-block A panel: 4 threads/row, each converts 64 fp32 -> 64 fp8 + norm part ---
  {
    int arow = tid >> 2;                 // 0..63
    int part = tid & 3;                  // 64-float chunk
    const float* xsrc = X + (size_t)(rowBase + arow) * D_DIM + part * 64;
    float ss = 0.0f;
    #pragma unroll
    for (int g4 = 0; g4 < 4; ++g4) {     // 4 granules of 16 fp8 bytes each
      i32x4 pk;
      #pragma unroll
      for (int d = 0; d < 4; ++d) {
        f32x4 v = *(const f32x4*)(xsrc + g4 * 16 + d * 4);
        ss += v[0]*v[0] + v[1]*v[1] + v[2]*v[2] + v[3]*v[3];
        int p = __builtin_amdgcn_cvt_pk_fp8_f32(v[0], v[1], 0, false);
        p = __builtin_amdgcn_cvt_pk_fp8_f32(v[2], v[3], p, true);
        pk[d] = p;
      }
      int gg = part * 4 + g4;            // global granule 0..15 in row
      *(i32x4*)(Al + arow * D_DIM + ((gg ^ (arow & 15)) << 4)) = pk;
    }
    ss += __shfl_xor(ss, 1);
    ss += __shfl_xor(ss, 2);
    if (part == 0) sx2[arow] = ss;
  }

  asm volatile("s_waitcnt vmcnt(0)" ::: "memory");
  __syncthreads();                       // tile 0 staged + Al/sx2/sy2l visible

  const unsigned char* Abase = Al + (wr * 32 + (l & 31)) * D_DIM + ((l >> 5) << 3);
  const unsigned char* Bbase = Bl + (wc * 32 + (l & 31)) * D_DIM + ((l >> 5) << 3);
  int rb0 = wr * 32 + 4 * (l >> 5);
  float sxv[16];
  #pragma unroll
  for (int q = 0; q < 16; ++q)           // hoist row norms to registers (static idx)
    sxv[q] = sx2[rb0 + (q & 3) + 8 * (q >> 2)];

  #pragma unroll 1
  for (int tt = 0; tt < NT2; ++tt) {
    // steady state queue per wave/tile = [4 staging][16 stores]; vmcnt(16) drains
    // old stores + all 4 staging ops, leaves 16 newest stores in flight (m135).
    if (tt) {
      asm volatile("s_waitcnt vmcnt(16)" ::: "memory");
      __builtin_amdgcn_s_barrier();      // Bl staged by ALL waves
    }
    __builtin_amdgcn_sched_barrier(0);

    // --- compute: K=256 in 16 x v_mfma_f32_32x32x16_fp8_fp8 (one 32x32 per wave) ---
    f32x16 acc = {};
    #pragma unroll
    for (int kk = 0; kk < 16; ++kk) {
      int ca = (kk ^ sk) << 4;
      i64t a = *(const i64t*)(Abase + ca);
      i64t b = *(const i64t*)(Bbase + ca);
      acc = __builtin_amdgcn_mfma_f32_32x32x16_fp8_fp8(a, b, acc, 0, 0, 0);
    }
    __builtin_amdgcn_s_barrier();        // all waves done reading Bl -> restage safe
    asm volatile("" ::: "memory");

    // --- issue NEXT tile's staging (4 vmem ops) BEFORE this tile's stores ---
    if (tt + 1 < NT2) {
      int colN = colBase + (tt + 1) * PN;
      #pragma unroll
      for (int q = 0; q < 4; ++q) {
        int c = tid + 256 * q;
        int row = c >> 4, g = c & 15;
        GLOAD_LDS(Yq + (size_t)(colN + row) * D_DIM + ((g ^ (row & 15)) << 4), Bl + c * 16);
      }
    }
    asm volatile("" ::: "memory");       // keep stores below the staging issues

    // --- epilogue: exp + 16 PLAIN dword stores (half-wave = one full 128B line) ---
    // C/D layout: col = l&31, row = (q&3) + 8*(q>>2) + 4*(l>>5)   [m74/m101]
    float sy = sy2l[tt * PN + wc * 32 + (l & 31)];
    float* base = Out + (size_t)(rowBase + rb0) * MSZ + colBase + tt * PN + wc * 32 + (l & 31);
    #pragma unroll
    for (int q = 0; q < 16; ++q) {
      int rpat = (q & 3) + 8 * (q >> 2);
      float d = fmaf(-2.0f, acc[q], sxv[q] + sy);
      base[(size_t)rpat * MSZ] = __expf(-fmaxf(d, 0.0f));
    }
    asm volatile("" ::: "memory");
  }
}

// ---------------- fallback (bf16, self-contained, used only if ws too small) ----------------
__global__ __launch_bounds__(256, 2)
void rbf_mfma_kernel(const float* __restrict__ X, const float* __restrict__ Y,
                     float* __restrict__ Out) {
  __shared__ unsigned short As[128 * 64];
  __shared__ unsigned short Bs[128 * 64];
  __shared__ float sx2[128];
  __shared__ float sy2[128];
  int bid = blockIdx.x;
  int cpx = gridDim.x >> 3;
  int swz = (bid & 7) * cpx + (bid >> 3);
  int bm = swz >> 6, bn = swz & 63;
  int rowBase = bm * 128, colBase = bn * 128;
  int tid = threadIdx.x;
  int l = tid & 63;
  int w = tid >> 6;
  int wr = w >> 1, wc = w & 1;
  f32x4 acc[4][4] = {};
  float assq[4] = {0.f,0.f,0.f,0.f};
  float bssq[4] = {0.f,0.f,0.f,0.f};
  for (int ks = 0; ks < D_DIM / 64; ++ks) {
    if (ks) __syncthreads();
    #pragma unroll
    for (int p = 0; p < 4; ++p) {
      int c = tid + 256 * p;
      int r = c >> 3;
      int kc = c & 7;
      const float* gx = X + (size_t)(rowBase + r) * D_DIM + ks * 64 + kc * 8;
      const float* gy = Y + (size_t)(colBase + r) * D_DIM + ks * 64 + kc * 8;
      f32x4 xa = *(const f32x4*)gx;
      f32x4 xb = *(const f32x4*)(gx + 4);
      f32x4 ya = *(const f32x4*)gy;
      f32x4 yb = *(const f32x4*)(gy + 4);
      #pragma unroll
      for (int j = 0; j < 4; ++j) {
        assq[p] += xa[j]*xa[j] + xb[j]*xb[j];
        bssq[p] += ya[j]*ya[j] + yb[j]*yb[j];
      }
      union { bf16x8 v; unsigned short u[8]; } pa, pb;
      #pragma unroll
      for (int j = 0; j < 4; ++j) {
        pa.u[j] = f2bf(xa[j]);  pa.u[j+4] = f2bf(xb[j]);
        pb.u[j] = f2bf(ya[j]);  pb.u[j+4] = f2bf(yb[j]);
      }
      int boff = (r * 128 + kc * 16) ^ ((r & 7) << 4);
      *(bf16x8*)((char*)As + boff) = pa.v;
      *(bf16x8*)((char*)Bs + boff) = pb.v;
    }
    __syncthreads();
    #pragma unroll
    for (int kk = 0; kk < 2; ++kk) {
      bf16x8 af[4], bfv[4];
      #pragma unroll
      for (int i = 0; i < 4; ++i) {
        int ra = wr*64 + i*16 + (l & 15);
        int offa = (ra * 128 + kk*64 + (l >> 4) * 16) ^ ((ra & 7) << 4);
        af[i] = *(bf16x8*)((char*)As + offa);
        int rb = wc*64 + i*16 + (l & 15);
        int offb = (rb * 128 + kk*64 + (l >> 4) * 16) ^ ((rb & 7) << 4);
        bfv[i] = *(bf16x8*)((char*)Bs + offb);
      }
      #pragma unroll
      for (int i = 0; i < 4; ++i)
        #pragma unroll
        for (int j = 0; j < 4; ++j)
          acc[i][j] = __builtin_amdgcn_mfma_f32_16x16x32_bf16(af[i], bfv[j], acc[i][j], 0, 0, 0);
    }
  }
  #pragma unroll
  for (int p = 0; p < 4; ++p) {
    float a = assq[p], b = bssq[p];
    a += __shfl_xor(a, 1); b += __shfl_xor(b, 1);
    a += __shfl_xor(a, 2); b += __shfl_xor(b, 2);
    a += __shfl_xor(a, 4); b += __shfl_xor(b, 4);
    if ((tid & 7) == 0) {
      int r = (tid >> 3) + 32 * p;
      sx2[r] = a;
      sy2[r] = b;
    }
  }
  __syncthreads();
  #pragma unroll
  for (int i = 0; i < 4; ++i)
    #pragma unroll
    for (int j = 0; j < 4; ++j)
      #pragma unroll
      for (int q = 0; q < 4; ++q) {
        int rn = wr*64 + i*16 + (l >> 4) * 4 + q;
        int cm = wc*64 + j*16 + (l & 15);
        float d2 = sx2[rn] + sy2[cm] - 2.0f * acc[i][j][q];
        Out[(size_t)(rowBase + rn) * MSZ + (colBase + cm)] = __expf(-fmaxf(d2, 0.0f));
      }
}

extern "C" void kernel_launch(void* const* d_in, const int* in_sizes, int n_in,
                              void* d_out, int out_size, void* d_ws, size_t ws_size,
                              hipStream_t stream) {
  const float* X = (const float*)d_in[0];
  const float* Y = (const float*)d_in[1];
  float* Out = (float*)d_out;
  const size_t QB = (size_t)MSZ * D_DIM;               // 2 MiB (fp8 Y)
  const size_t NEED = QB + (size_t)MSZ * 4;            // Yq + y2
  if (ws_size >= NEED) {
    unsigned char* Yq = (unsigned char*)d_ws;
    float* y2 = (float*)(Yq + QB);
    prep_y<<<dim3(2048), dim3(256), 0, stream>>>(Y, Yq, y2);
    rbf_main<<<dim3(1024), dim3(256), 0, stream>>>(X, Yq, y2, Out);
  } else {
    rbf_mfma_kernel<<<dim3(64 * 64), dim3(256), 0, stream>>>(X, Y, Out);
  }
}

// Round 12
// 64.321 us; speedup vs baseline: 1.2975x; 1.0375x over previous
//
#include <hip/hip_runtime.h>
#include <hip/hip_bf16.h>

typedef __attribute__((ext_vector_type(4))) float f32x4;
typedef __attribute__((ext_vector_type(8))) short bf16x8;
typedef __attribute__((ext_vector_type(16))) float f32x16;
typedef long i64t;

#define MSZ 8192
#define D_DIM 256

#define GLOAD_LDS(g, s) __builtin_amdgcn_global_load_lds( \
    (const __attribute__((address_space(1))) unsigned int*)(g), \
    (__attribute__((address_space(3))) unsigned int*)(s), 16, 0, 0)

__device__ __forceinline__ unsigned short f2bf(float f) {
  __hip_bfloat16 h = __float2bfloat16(f);
  unsigned short u; __builtin_memcpy(&u, &h, 2); return u;
}

// ---------------- pass 1: fp32 -> fp8(e4m3) copies + exact fp32 row norms ----------------
__global__ __launch_bounds__(256)
void prep_fp8(const float* __restrict__ X, const float* __restrict__ Y,
              unsigned char* __restrict__ Xq, unsigned char* __restrict__ Yq,
              float* __restrict__ x2, float* __restrict__ y2) {
  int gw = (blockIdx.x * 256 + threadIdx.x) >> 6;   // one wave per row; 16384 waves
  int l = threadIdx.x & 63;
  int row = gw & (MSZ - 1);
  const float* src = (gw < MSZ ? X : Y) + (size_t)row * D_DIM + l * 4;
  f32x4 v = *(const f32x4*)src;
  float ss = v[0]*v[0] + v[1]*v[1] + v[2]*v[2] + v[3]*v[3];
  int p = __builtin_amdgcn_cvt_pk_fp8_f32(v[0], v[1], 0, false);
  p = __builtin_amdgcn_cvt_pk_fp8_f32(v[2], v[3], p, true);
  unsigned char* dst = (gw < MSZ ? Xq : Yq) + (size_t)row * D_DIM + l * 4;
  *(unsigned int*)dst = (unsigned int)p;
  #pragma unroll
  for (int m = 1; m < 64; m <<= 1) ss += __shfl_xor(ss, m);
  if (l == 0) (gw < MSZ ? x2 : y2)[row] = ss;
}

// ---- pass 2: barrier-free main loop. A panel shared read-only; B wave-private;
// ---- each wave self-paces with its own vmcnt. Zero __syncthreads in the loop.
__global__ __launch_bounds__(256, 3)
void rbf_main(const unsigned char* __restrict__ Xq, const unsigned char* __restrict__ Yq,
              const float* __restrict__ X2, const float* __restrict__ Y2,
              float* __restrict__ Out) {
  __shared__ __align__(16) unsigned char Al[64 * D_DIM];      // 16 KB shared A panel
  __shared__ __align__(16) unsigned char Bl[4][32 * D_DIM];   // 4 x 8 KB private B
  __shared__ float sy2l[1024];                                 // col norms for the 1024-span

  int bid = blockIdx.x;                  // 1024 blocks; bijective XCD swizzle (1024%8==0)
  int swz = (bid & 7) * 128 + (bid >> 3);
  int bm = swz >> 3;                     // 128 row-panels of 64
  int cg = swz & 7;                      // 8 column groups of 1024
  int rowBase = bm * 64;
  int colBase = cg * 1024;

  int tid = threadIdx.x;
  int l = tid & 63;
  int w = tid >> 6;                      // wave -> private 32-col group per step
  int sk = l & 15;                       // LDS granule swizzle key
  int h = l >> 5;                        // half-wave

  *(f32x4*)&sy2l[tid * 4] = *(const f32x4*)&Y2[colBase + tid * 4];

  // row norms -> 8 f32x4 regs (static layout matches C/D rows rpat+4h)
  f32x4 sxv[2][4];
  #pragma unroll
  for (int i = 0; i < 2; ++i)
    #pragma unroll
    for (int g = 0; g < 4; ++g)
      sxv[i][g] = *(const f32x4*)&X2[rowBase + i * 32 + g * 8 + 4 * h];

  // A panel staging (whole block cooperates; swizzled source granules, m173)
  #pragma unroll
  for (int q = 0; q < 4; ++q) {
    int c = tid + 256 * q;               // granule 0..1023
    int row = c >> 4, g = c & 15;
    GLOAD_LDS(Xq + (size_t)(rowBase + row) * D_DIM + ((g ^ (row & 15)) << 4), Al + c * 16);
  }
  // B step-0 staging: wave's own 8 KB quadrant (8 ops)
  #pragma unroll
  for (int q = 0; q < 8; ++q) {
    int c = l + 64 * q;                  // granule 0..511
    int row = c >> 4, g = c & 15;
    GLOAD_LDS(Yq + (size_t)(colBase + w * 32 + row) * D_DIM + ((g ^ (row & 15)) << 4),
              Bl[w] + c * 16);
  }
  asm volatile("s_waitcnt vmcnt(0)" ::: "memory");
  __syncthreads();                       // ONLY barrier: A visible to all waves

  const unsigned char* Abase = Al + (l & 31) * D_DIM + (h << 3);
  const unsigned char* Bbase = Bl[w] + (l & 31) * D_DIM + (h << 3);

  #pragma unroll 1
  for (int t = 0; t < 8; ++t) {
    // per-wave pacing: queue = [<=32 stores(t-1)][8 staging(t)]; vmcnt(32)
    // drains the staging (in-order, m135) without draining stores.
    if (t) {
      asm volatile("s_waitcnt vmcnt(32)" ::: "memory");
      __builtin_amdgcn_sched_barrier(0);
    }

    // K=256: 16 x (1 private-B read, 2 shared-A reads, 2 MFMA)
    f32x16 acc0 = {}, acc1 = {};
    #pragma unroll
    for (int kk = 0; kk < 16; ++kk) {
      int ca = (kk ^ sk) << 4;
      i64t b  = *(const i64t*)(Bbase + ca);
      i64t a0 = *(const i64t*)(Abase + ca);
      i64t a1 = *(const i64t*)(Abase + 32 * D_DIM + ca);
      acc0 = __builtin_amdgcn_mfma_f32_32x32x16_fp8_fp8(a0, b, acc0, 0, 0, 0);
      acc1 = __builtin_amdgcn_mfma_f32_32x32x16_fp8_fp8(a1, b, acc1, 0, 0, 0);
    }
    asm volatile("s_waitcnt lgkmcnt(0)" ::: "memory");   // B reads retired before restage
    __builtin_amdgcn_sched_barrier(0);

    // restage own quadrant for t+1 (no barrier needed: private buffer)
    if (t + 1 < 8) {
      int colN = colBase + (t + 1) * 128 + w * 32;
      #pragma unroll
      for (int q = 0; q < 8; ++q) {
        int c = l + 64 * q;
        int row = c >> 4, g = c & 15;
        GLOAD_LDS(Yq + (size_t)(colN + row) * D_DIM + ((g ^ (row & 15)) << 4), Bl[w] + c * 16);
      }
    }
    asm volatile("" ::: "memory");       // stores stay below staging issues

    // epilogue: exp + 32 plain dword stores (half-wave = one full 128B line)
    // C/D: col = l&31, row = (q&3) + 8*(q>>2) + 4*(l>>5)   [m74/m101]
    float sy = sy2l[t * 128 + w * 32 + (l & 31)];
    float* base = Out + (size_t)(rowBase + 4 * h) * MSZ + colBase + t * 128 + w * 32 + (l & 31);
    #pragma unroll
    for (int q = 0; q < 16; ++q) {
      int rpat = (q & 3) + 8 * (q >> 2);
      float d0 = fmaf(-2.0f, acc0[q], sxv[0][q >> 2][q & 3] + sy);
      float d1 = fmaf(-2.0f, acc1[q], sxv[1][q >> 2][q & 3] + sy);
      base[(size_t)rpat * MSZ]        = __expf(-fmaxf(d0, 0.0f));
      base[(size_t)(rpat + 32) * MSZ] = __expf(-fmaxf(d1, 0.0f));
    }
    asm volatile("" ::: "memory");
  }
}

// ---------------- fallback (bf16, self-contained, used only if ws too small) ----------------
__global__ __launch_bounds__(256, 2)
void rbf_mfma_kernel(const float* __restrict__ X, const float* __restrict__ Y,
                     float* __restrict__ Out) {
  __shared__ unsigned short As[128 * 64];
  __shared__ unsigned short Bs[128 * 64];
  __shared__ float sx2[128];
  __shared__ float sy2[128];
  int bid = blockIdx.x;
  int cpx = gridDim.x >> 3;
  int swz = (bid & 7) * cpx + (bid >> 3);
  int bm = swz >> 6, bn = swz & 63;
  int rowBase = bm * 128, colBase = bn * 128;
  int tid = threadIdx.x;
  int l = tid & 63;
  int w = tid >> 6;
  int wr = w >> 1, wc = w & 1;
  f32x4 acc[4][4] = {};
  float assq[4] = {0.f,0.f,0.f,0.f};
  float bssq[4] = {0.f,0.f,0.f,0.f};
  for (int ks = 0; ks < D_DIM / 64; ++ks) {
    if (ks) __syncthreads();
    #pragma unroll
    for (int p = 0; p < 4; ++p) {
      int c = tid + 256 * p;
      int r = c >> 3;
      int kc = c & 7;
      const float* gx = X + (size_t)(rowBase + r) * D_DIM + ks * 64 + kc * 8;
      const float* gy = Y + (size_t)(colBase + r) * D_DIM + ks * 64 + kc * 8;
      f32x4 xa = *(const f32x4*)gx;
      f32x4 xb = *(const f32x4*)(gx + 4);
      f32x4 ya = *(const f32x4*)gy;
      f32x4 yb = *(const f32x4*)(gy + 4);
      #pragma unroll
      for (int j = 0; j < 4; ++j) {
        assq[p] += xa[j]*xa[j] + xb[j]*xb[j];
        bssq[p] += ya[j]*ya[j] + yb[j]*yb[j];
      }
      union { bf16x8 v; unsigned short u[8]; } pa, pb;
      #pragma unroll
      for (int j = 0; j < 4; ++j) {
        pa.u[j] = f2bf(xa[j]);  pa.u[j+4] = f2bf(xb[j]);
        pb.u[j] = f2bf(ya[j]);  pb.u[j+4] = f2bf(yb[j]);
      }
      int boff = (r * 128 + kc * 16) ^ ((r & 7) << 4);
      *(bf16x8*)((char*)As + boff) = pa.v;
      *(bf16x8*)((char*)Bs + boff) = pb.v;
    }
    __syncthreads();
    #pragma unroll
    for (int kk = 0; kk < 2; ++kk) {
      bf16x8 af[4], bfv[4];
      #pragma unroll
      for (int i = 0; i < 4; ++i) {
        int ra = wr*64 + i*16 + (l & 15);
        int offa = (ra * 128 + kk*64 + (l >> 4) * 16) ^ ((ra & 7) << 4);
        af[i] = *(bf16x8*)((char*)As + offa);
        int rb = wc*64 + i*16 + (l & 15);
        int offb = (rb * 128 + kk*64 + (l >> 4) * 16) ^ ((rb & 7) << 4);
        bfv[i] = *(bf16x8*)((char*)Bs + offb);
      }
      #pragma unroll
      for (int i = 0; i < 4; ++i)
        #pragma unroll
        for (int j = 0; j < 4; ++j)
          acc[i][j] = __builtin_amdgcn_mfma_f32_16x16x32_bf16(af[i], bfv[j], acc[i][j], 0, 0, 0);
    }
  }
  #pragma unroll
  for (int p = 0; p < 4; ++p) {
    float a = assq[p], b = bssq[p];
    a += __shfl_xor(a, 1); b += __shfl_xor(b, 1);
    a += __shfl_xor(a, 2); b += __shfl_xor(b, 2);
    a += __shfl_xor(a, 4); b += __shfl_xor(b, 4);
    if ((tid & 7) == 0) {
      int r = (tid >> 3) + 32 * p;
      sx2[r] = a;
      sy2[r] = b;
    }
  }
  __syncthreads();
  #pragma unroll
  for (int i = 0; i < 4; ++i)
    #pragma unroll
    for (int j = 0; j < 4; ++j)
      #pragma unroll
      for (int q = 0; q < 4; ++q) {
        int rn = wr*64 + i*16 + (l >> 4) * 4 + q;
        int cm = wc*64 + j*16 + (l & 15);
        float d2 = sx2[rn] + sy2[cm] - 2.0f * acc[i][j][q];
        Out[(size_t)(rowBase + rn) * MSZ + (colBase + cm)] = __expf(-fmaxf(d2, 0.0f));
      }
}

extern "C" void kernel_launch(void* const* d_in, const int* in_sizes, int n_in,
                              void* d_out, int out_size, void* d_ws, size_t ws_size,
                              hipStream_t stream) {
  const float* X = (const float*)d_in[0];
  const float* Y = (const float*)d_in[1];
  float* Out = (float*)d_out;
  const size_t QB = (size_t)MSZ * D_DIM;               // 2 MiB per matrix (fp8)
  const size_t NEED = QB * 2 + (size_t)MSZ * 4 * 2;    // Xq+Yq+x2+y2
  if (ws_size >= NEED) {
    unsigned char* Xq = (unsigned char*)d_ws;
    unsigned char* Yq = Xq + QB;
    float* x2 = (float*)(Yq + QB);
    float* y2 = x2 + MSZ;
    prep_fp8<<<dim3(4096), dim3(256), 0, stream>>>(X, Y, Xq, Yq, x2, y2);
    rbf_main<<<dim3(1024), dim3(256), 0, stream>>>(Xq, Yq, x2, y2, Out);
  } else {
    rbf_mfma_kernel<<<dim3(64 * 64), dim3(256), 0, stream>>>(X, Y, Out);
  }
}